// Round 1
// baseline (192.299 us; speedup 1.0000x reference)
//
#include <hip/hip_runtime.h>

// ColorHistogramLoss: soft histogram (Gaussian kernel, 64 bins) over
// pred/target (4,3,256,256) fp32, normalized, cumsum, mean |cdf diff|.
//
// v2: truncated-Gaussian (±8 bins) + ratio-recurrence histogram.
//   Per pixel: 2x v_exp_f32 total; per tap: 2 v_mul + ds_add_f32.
//   Replaces 64 full exp-taps/pixel (trans-issue-bound, ~30us) with 17
//   exp-free taps into a per-wave padded LDS histogram (~6us predicted).
//
// Structure:
//   zero_ws     : zero 24*64-float histogram scratch in d_ws
//   hist_kernel : 768 blocks x 256 thr; per-wave 80-entry LDS hist,
//                 ds_add_f32 scatter, LDS combine, global atomics
//   final_kernel: 1 block x 768 thr (12 waves); per-wave scan -> cdf ->
//                 |diff| -> mean scalar to d_out[0]

#define BINS 64
#define NCH 12            // B*C = 4*3
#define HW 65536          // 256*256
#define BPC 32            // pixel-chunks (blocks) per channel-image
#define PIX_PER_BLOCK (HW / BPC)              // 2048
#define THREADS 256
#define R 8               // Gaussian support radius in bins (w <= e^-32 beyond)
#define WIN (2 * R + 1)   // 17 taps
#define PADBINS (BINS + 2 * R)   // 80: pad absorbs edge windows, branch-free
#define NWAVES (THREADS / 64)    // 4

__device__ __forceinline__ float fast_exp2(float x) {
#if __has_builtin(__builtin_amdgcn_exp2f)
    return __builtin_amdgcn_exp2f(x);   // v_exp_f32
#else
    return exp2f(x);
#endif
}

__global__ void zero_ws(float* ws, int n) {
    int i = blockIdx.x * blockDim.x + threadIdx.x;
    if (i < n) ws[i] = 0.0f;
}

// weight for bin j: exp(-d^2/2), d = x*64 - (j+0.5) = (i+f) - j, sigma = 1 bin.
// Factor w_k = exp(-(k-f)^2/2) = [exp(-f^2/2) * B^-R] * B^k+R... via:
//   P_0   = exp(-f^2/2 - R*f)           (one exp2)
//   B     = exp(f)                      (one exp2)
//   w_t   = CK[t] * P_t ;  P_{t+1} = P_t * B      (t = 0..16, k = t-R)
// CK[t] = exp(-(t-R)^2/2) are compile-time literals.
__global__ __launch_bounds__(THREADS) void hist_kernel(
        const float* __restrict__ pred,
        const float* __restrict__ target,
        float* __restrict__ hist) {
    constexpr float CK[WIN] = {
        1.2664165549094176e-14f, 2.2897348456455526e-11f, 1.5229979744712628e-08f,
        3.7266531720786709e-06f, 3.3546262790251185e-04f, 1.1108996538242306e-02f,
        1.3533528323661270e-01f, 6.0653065971263342e-01f, 1.0f,
        6.0653065971263342e-01f, 1.3533528323661270e-01f, 1.1108996538242306e-02f,
        3.3546262790251185e-04f, 3.7266531720786709e-06f, 1.5229979744712628e-08f,
        2.2897348456455526e-11f, 1.2664165549094176e-14f };

    const int blk   = blockIdx.x;
    const int ch    = blk / BPC;        // 0..23 (0..11 pred, 12..23 target)
    const int chunk = blk % BPC;
    const float* src = (ch < NCH) ? (pred + (size_t)ch * HW)
                                  : (target + (size_t)(ch - NCH) * HW);

    // per-wave private padded histogram: no inter-wave collisions;
    // intra-wave same-bin ds_add_f32 collisions HW-serialized.
    __shared__ float h[NWAVES][PADBINS];
    for (int t = threadIdx.x; t < NWAVES * PADBINS; t += THREADS)
        (&h[0][0])[t] = 0.0f;
    __syncthreads();

    float* hw_ = h[threadIdx.x >> 6];

    // 512 float4 per block; thread t loads f4[t] and f4[t+256] (coalesced).
    const float4* src4 = (const float4*)(src + chunk * PIX_PER_BLOCK);
    float4 a = src4[threadIdx.x];
    float4 b = src4[threadIdx.x + THREADS];
    float px[8] = {a.x, a.y, a.z, a.w, b.x, b.y, b.z, b.w};  // static-indexed

    const float L = 1.4426950408889634f;   // log2(e)

    #pragma unroll
    for (int p = 0; p < 8; ++p) {
        float xt = px[p] * 64.0f - 0.5f;       // bin-center units, [-0.5, 63.5)
        float fi = rintf(xt);
        fi = fminf(fmaxf(fi, 0.0f), 63.0f);    // v_med3-style clamp (defensive)
        float f  = xt - fi;                    // [-0.5, 0.5]
        int   i  = (int)fi;                    // nearest bin, 0..63
        // P = exp(-f^2/2 - R*f) ; B = exp(f)   (log2 domain)
        float P  = fast_exp2(-(0.5f * L) * (f * f + (float)(2 * R) * f));
        float B  = fast_exp2(L * f);
        float* hp = hw_ + i;                   // padded pos i..i+16 = bins i-R..i+R
        #pragma unroll
        for (int t = 0; t < WIN; ++t) {
            atomicAdd(&hp[t], CK[t] * P);      // ds_add_f32, offset:t*4
            P *= B;
        }
    }

    __syncthreads();
    // combine the 4 wave-copies (discard pad) and push to global.
    if (threadIdx.x < BINS) {
        float s = 0.0f;
        #pragma unroll
        for (int c = 0; c < NWAVES; ++c) s += h[c][R + threadIdx.x];
        atomicAdd(&hist[ch * BINS + threadIdx.x], s);
    }
}

__global__ __launch_bounds__(NCH * 64) void final_kernel(
        const float* __restrict__ hist, float* __restrict__ out) {
    const int w    = threadIdx.x >> 6;   // 0..11 -> (b,c) channel
    const int lane = threadIdx.x & 63;   // bin

    float ph = hist[w * BINS + lane];
    float th = hist[(NCH + w) * BINS + lane];

    // inclusive scan over bins (wave64 shfl_up)
    float ps = ph, ts = th;
    #pragma unroll
    for (int d = 1; d < 64; d <<= 1) {
        float a = __shfl_up(ps, d, 64);
        float b = __shfl_up(ts, d, 64);
        if (lane >= d) { ps += a; ts += b; }
    }
    float ptot = __shfl(ps, 63, 64);
    float ttot = __shfl(ts, 63, 64);
    float pc = ps / (ptot + 1e-8f);
    float tc = ts / (ttot + 1e-8f);
    float dv = fabsf(pc - tc);

    // wave reduce
    #pragma unroll
    for (int k = 32; k >= 1; k >>= 1) dv += __shfl_xor(dv, k, 64);

    __shared__ float warr[NCH];
    if (lane == 0) warr[w] = dv;
    __syncthreads();
    if (threadIdx.x == 0) {
        float s = 0.0f;
        #pragma unroll
        for (int i = 0; i < NCH; ++i) s += warr[i];
        out[0] = s / (float)(NCH * BINS);
    }
}

extern "C" void kernel_launch(void* const* d_in, const int* in_sizes, int n_in,
                              void* d_out, int out_size, void* d_ws, size_t ws_size,
                              hipStream_t stream) {
    const float* pred   = (const float*)d_in[0];
    const float* target = (const float*)d_in[1];
    float* hist = (float*)d_ws;          // 2*NCH*BINS = 1536 floats
    float* out  = (float*)d_out;

    zero_ws<<<dim3((2 * NCH * BINS + 255) / 256), dim3(256), 0, stream>>>(
        hist, 2 * NCH * BINS);
    hist_kernel<<<dim3(2 * NCH * BPC), dim3(THREADS), 0, stream>>>(
        pred, target, hist);
    final_kernel<<<dim3(1), dim3(NCH * 64), 0, stream>>>(hist, out);
}